// Round 6
// baseline (217.345 us; speedup 1.0000x reference)
//
#include <hip/hip_runtime.h>

#define B_ 8
#define C_ 256
#define C8_ 32
#define N_ 4096

typedef __bf16 bf16;
typedef __bf16 bf16x4 __attribute__((ext_vector_type(4)));
typedef __bf16 bf16x8 __attribute__((ext_vector_type(8)));
typedef float f32x4 __attribute__((ext_vector_type(4)));
typedef float f32x16 __attribute__((ext_vector_type(16)));

#if __has_builtin(__builtin_amdgcn_exp2f)
#define EXP2 __builtin_amdgcn_exp2f
#else
#define EXP2 exp2f
#endif

#define CVTPK(lo, hi) ({ unsigned int _w;                                     \
  asm("v_cvt_pk_bf16_f32 %0, %1, %2" : "=v"(_w) : "v"(lo), "v"(hi)); _w; })
#define LSWAP(a, b) asm("v_permlane32_swap_b32 %0, %1" : "+v"(a), "+v"(b))

// ---------------- weights f32 -> bf16 (once) --------------------------------
__global__ __launch_bounds__(256) void k_convw(const float* __restrict__ wq,
    const float* __restrict__ wk, const float* __restrict__ wv,
    bf16* __restrict__ Wb) {
  int i = (blockIdx.x * 256 + threadIdx.x) * 4;
  const float* src; int off;
  if (i < 8192) { src = wq; off = i; }
  else if (i < 16384) { src = wk; off = i - 8192; }
  else { src = wv; off = i - 16384; }
  f32x4 v = *reinterpret_cast<const f32x4*>(src + off);
  bf16x4 o;
  o[0] = (bf16)v[0]; o[1] = (bf16)v[1]; o[2] = (bf16)v[2]; o[3] = (bf16)v[3];
  *reinterpret_cast<bf16x4*>(Wb + i) = o;
}

// ---------------- transpose + convert: x[b][c][n] f32 -> xT[b][n][c] bf16 ----
__global__ __launch_bounds__(256) void k_transpose(const float* __restrict__ x,
                                                   bf16* __restrict__ xT) {
  __shared__ bf16 t[64][72];
  int bid = blockIdx.x;
  int b = bid & 7, rem = bid >> 3;
  int c0 = (rem >> 6) * 64, n0 = (rem & 63) * 64;
  int tid = threadIdx.x;
#pragma unroll
  for (int r = 0; r < 4; ++r) {
    int cc = r * 16 + (tid >> 4);
    int j = (tid & 15) * 4;
    f32x4 v = *reinterpret_cast<const f32x4*>(
        x + ((size_t)b * C_ + c0 + cc) * N_ + n0 + j);
    bf16x4 o;
    o[0] = (bf16)v[0]; o[1] = (bf16)v[1]; o[2] = (bf16)v[2]; o[3] = (bf16)v[3];
    *reinterpret_cast<bf16x4*>(&t[cc][j]) = o;
  }
  __syncthreads();
#pragma unroll
  for (int r = 0; r < 2; ++r) {
    int nn = r * 32 + (tid >> 3);
    int c8 = (tid & 7) * 8;
    bf16x8 o;
#pragma unroll
    for (int k = 0; k < 8; ++k) o[k] = t[c8 + k][nn];
    *reinterpret_cast<bf16x8*>(
        xT + ((size_t)b * N_ + n0 + nn) * C_ + c0 + c8) = o;
  }
}

// ------------- Q/K projection (Q scaled by log2e), bf16 weights -------------
__global__ __launch_bounds__(256) void k_proj_qk(const bf16* __restrict__ xT,
    const bf16* __restrict__ Wb,
    const float* __restrict__ bq, const float* __restrict__ bk,
    bf16* __restrict__ Qt, bf16* __restrict__ Kt) {
  int bid = blockIdx.x;
  int b = bid & 7, nt = bid >> 3;
  const bf16* W = Wb + (blockIdx.y ? 8192 : 0);
  const float* bias = blockIdx.y ? bk : bq;
  bf16* Out = blockIdx.y ? Kt : Qt;
  float scl = blockIdx.y ? 1.0f : 1.44269504f;
  int tid = threadIdx.x, lane = tid & 63, w = tid >> 6;
  int ln = lane & 31, h = lane >> 5;
  int n0 = nt * 128 + w * 32;
  const bf16* xp = xT + ((size_t)b * N_ + n0 + ln) * C_ + h * 8;
  const bf16* wp = W + (size_t)ln * C_ + h * 8;
  f32x16 acc;
#pragma unroll
  for (int r = 0; r < 16; ++r) acc[r] = 0.f;
#pragma unroll
  for (int ck = 0; ck < C_; ck += 16) {
    bf16x8 af = *reinterpret_cast<const bf16x8*>(xp + ck);
    bf16x8 bfg = *reinterpret_cast<const bf16x8*>(wp + ck);
    acc = __builtin_amdgcn_mfma_f32_32x32x16_bf16(af, bfg, acc, 0, 0, 0);
  }
  float bb = bias[ln];
#pragma unroll
  for (int r = 0; r < 16; ++r) {
    int n = n0 + (r & 3) + 8 * (r >> 2) + 4 * h;
    Out[((size_t)b * N_ + n) * C8_ + ln] = (bf16)((acc[r] + bb) * scl);
  }
}

// ------------- V projection -> TILED layout Vt[b][m/32][c][m%32] bf16 -------
__global__ __launch_bounds__(256) void k_proj_v(const bf16* __restrict__ xT,
    const bf16* __restrict__ Wb, const float* __restrict__ bv,
    bf16* __restrict__ Vt) {
  int bid = blockIdx.x;
  int b = bid & 7, rem = bid >> 3;
  int ot = rem >> 5, nt = rem & 31;
  int tid = threadIdx.x, lane = tid & 63, w = tid >> 6;
  int ln = lane & 31, h = lane >> 5;
  int o0 = ot * 32;
  int n0 = nt * 128 + w * 32;
  const bf16* wp = Wb + 16384 + (size_t)(o0 + ln) * C_ + h * 8;
  const bf16* xp = xT + ((size_t)b * N_ + n0 + ln) * C_ + h * 8;
  f32x16 acc;
#pragma unroll
  for (int r = 0; r < 16; ++r) acc[r] = 0.f;
#pragma unroll
  for (int ck = 0; ck < C_; ck += 16) {
    bf16x8 afg = *reinterpret_cast<const bf16x8*>(wp + ck);
    bf16x8 bfg = *reinterpret_cast<const bf16x8*>(xp + ck);
    acc = __builtin_amdgcn_mfma_f32_32x32x16_bf16(afg, bfg, acc, 0, 0, 0);
  }
  int mt = n0 >> 5;
  bf16* base = Vt + (size_t)(b * 128 + mt) * 256 * 32;
#pragma unroll
  for (int r = 0; r < 16; ++r) {
    int c = o0 + (r & 3) + 8 * (r >> 2) + 4 * h;
    base[(size_t)c * 32 + ln] = (bf16)(acc[r] + bv[c]);
  }
}

// ---------------- flash attention: m-split waves, full 256 channels ---------
// 1024 blocks x 4 waves. Block = (b, 32-query tile). Wave w owns m-range
// [w*1024,(w+1)*1024): 32 iterations, each = {QK once, softmax once, 16 PV
// MFMAs over all 256 channels}. No duplicated work. 4-way merge at the end
// (pairwise-parallel through LDS).
__global__ __launch_bounds__(256, 2) void k_attn(const bf16* __restrict__ Qt,
    const bf16* __restrict__ Kt, const bf16* __restrict__ Vt,
    const float* __restrict__ x, float* __restrict__ out) {
  __shared__ float Ob[2][256][33];     // two parallel merge buffers
  __shared__ float sML[4][2][32];      // [wave][{M,L}][q]
  int bid = blockIdx.x;
  int b = bid & 7;                     // batch == XCD
  int qt = bid >> 3;
  int n0 = qt * 32;
  int tid = threadIdx.x, lane = tid & 63, w = tid >> 6;
  int ln = lane & 31, h = lane >> 5;

  const bf16* qp = Qt + ((size_t)b * N_ + n0 + ln) * C8_ + h * 8;
  bf16x8 qf0 = *reinterpret_cast<const bf16x8*>(qp);
  bf16x8 qf1 = *reinterpret_cast<const bf16x8*>(qp + 16);
  const bf16* Kbase = Kt + (size_t)b * N_ * C8_
                         + ((size_t)(w * 1024) + ln) * C8_ + h * 8;
  const bf16* Vbase = Vt + ((size_t)b * 128 + w * 32) * 8192
                         + (size_t)ln * 32 + h * 8;

  f32x16 o[8];
#pragma unroll
  for (int ct = 0; ct < 8; ++ct)
#pragma unroll
    for (int r = 0; r < 16; ++r) o[ct][r] = 0.f;
  float M = -1e30f, L = 0.f;

  bf16x8 kf0 = *reinterpret_cast<const bf16x8*>(Kbase);
  bf16x8 kf1 = *reinterpret_cast<const bf16x8*>(Kbase + 16);

#pragma unroll 2
  for (int it = 0; it < 32; ++it) {
    // ---- S = (K tile) x Q  (once per tile)
    f32x16 s;
#pragma unroll
    for (int r = 0; r < 16; ++r) s[r] = 0.f;
    s = __builtin_amdgcn_mfma_f32_32x32x16_bf16(kf0, qf0, s, 0, 0, 0);
    s = __builtin_amdgcn_mfma_f32_32x32x16_bf16(kf1, qf1, s, 0, 0, 0);

    // prefetch next K tile (consumed next iteration)
    int itn = it + 1 > 31 ? 31 : it + 1;
    bf16x8 kn0 = *reinterpret_cast<const bf16x8*>(Kbase + (size_t)itn * 1024);
    bf16x8 kn1 = *reinterpret_cast<const bf16x8*>(Kbase + (size_t)itn * 1024 + 16);

    // prestage V for ct 0..3 (latency hidden under softmax)
    const bf16* vt = Vbase + (size_t)it * 8192;
    bf16x8 vs[8];
#pragma unroll
    for (int j = 0; j < 8; ++j)
      vs[j] = *reinterpret_cast<const bf16x8*>(vt + (j >> 1) * 1024 + (j & 1) * 16);

    // ---- softmax (once per tile)
    float m0 = fmaxf(fmaxf(fmaxf(s[0], s[1]), fmaxf(s[2], s[3])),
                     fmaxf(fmaxf(s[4], s[5]), fmaxf(s[6], s[7])));
    float m1 = fmaxf(fmaxf(fmaxf(s[8], s[9]), fmaxf(s[10], s[11])),
                     fmaxf(fmaxf(s[12], s[13]), fmaxf(s[14], s[15])));
    float wm = fmaxf(m0, m1);
    wm = fmaxf(wm, __shfl_xor(wm, 32));
    bool resc = __any(wm > M + 8.f);     // defer-max (T13)
    if (resc) {
      float Mn = fmaxf(M, wm);
      float sc = EXP2(M - Mn);
      L *= sc;
#pragma unroll
      for (int ct = 0; ct < 8; ++ct)
#pragma unroll
        for (int r = 0; r < 16; ++r) o[ct][r] *= sc;
      M = Mn;
    }
#pragma unroll
    for (int r = 0; r < 16; ++r) s[r] = EXP2(s[r] - M);
    float q0 = (s[0] + s[1]) + (s[2] + s[3]);
    float q1 = (s[4] + s[5]) + (s[6] + s[7]);
    float q2 = (s[8] + s[9]) + (s[10] + s[11]);
    float q3 = (s[12] + s[13]) + (s[14] + s[15]);
    L += (q0 + q1) + (q2 + q3);

    // P -> bf16 frags in-register (T12)
    unsigned int c0 = CVTPK(s[0], s[1]),   c1 = CVTPK(s[2], s[3]);
    unsigned int c2 = CVTPK(s[4], s[5]),   c3 = CVTPK(s[6], s[7]);
    unsigned int c4 = CVTPK(s[8], s[9]),   c5 = CVTPK(s[10], s[11]);
    unsigned int c6 = CVTPK(s[12], s[13]), c7 = CVTPK(s[14], s[15]);
    LSWAP(c0, c2); LSWAP(c1, c3); LSWAP(c4, c6); LSWAP(c5, c7);
    union { unsigned int u[4]; bf16x8 v; } P0, P1;
    P0.u[0] = c0; P0.u[1] = c1; P0.u[2] = c2; P0.u[3] = c3;
    P1.u[0] = c4; P1.u[1] = c5; P1.u[2] = c6; P1.u[3] = c7;

    // ---- PV over all 256 channels (16 MFMAs)
    __builtin_amdgcn_s_setprio(1);
#pragma unroll
    for (int ct = 0; ct < 4; ++ct) {
      o[ct] = __builtin_amdgcn_mfma_f32_32x32x16_bf16(vs[2 * ct], P0.v, o[ct], 0, 0, 0);
      o[ct] = __builtin_amdgcn_mfma_f32_32x32x16_bf16(vs[2 * ct + 1], P1.v, o[ct], 0, 0, 0);
    }
#pragma unroll
    for (int ct = 4; ct < 8; ++ct) {
      bf16x8 vf0 = *reinterpret_cast<const bf16x8*>(vt + ct * 1024);
      bf16x8 vf1 = *reinterpret_cast<const bf16x8*>(vt + ct * 1024 + 16);
      o[ct] = __builtin_amdgcn_mfma_f32_32x32x16_bf16(vf0, P0.v, o[ct], 0, 0, 0);
      o[ct] = __builtin_amdgcn_mfma_f32_32x32x16_bf16(vf1, P1.v, o[ct], 0, 0, 0);
    }
    __builtin_amdgcn_s_setprio(0);

    kf0 = kn0; kf1 = kn1;
  }

  // ---- 4-way merge, pairwise-parallel ----
  L += __shfl_xor(L, 32);
  if (lane < 32) { sML[w][0][lane] = M; sML[w][1][lane] = L; }
  __syncthreads();
  float Ms = fmaxf(fmaxf(sML[0][0][ln], sML[1][0][ln]),
                   fmaxf(sML[2][0][ln], sML[3][0][ln]));
  float Lt = sML[0][1][ln] * EXP2(sML[0][0][ln] - Ms)
           + sML[1][1][ln] * EXP2(sML[1][0][ln] - Ms)
           + sML[2][1][ln] * EXP2(sML[2][0][ln] - Ms)
           + sML[3][1][ln] * EXP2(sML[3][0][ln] - Ms);
  float inv = 1.f / Lt;
  float a = EXP2(M - Ms);
  int half = w >> 1;                 // waves {0,1}->buf0, {2,3}->buf1
  if (!(w & 1)) {                    // waves 0,2 write
#pragma unroll
    for (int ct = 0; ct < 8; ++ct)
#pragma unroll
      for (int r = 0; r < 16; ++r) {
        int c = ct * 32 + (r & 3) + 8 * (r >> 2) + 4 * h;
        Ob[half][c][ln] = o[ct][r] * a;
      }
  }
  __syncthreads();
  if (w & 1) {                       // waves 1,3 add
#pragma unroll
    for (int ct = 0; ct < 8; ++ct)
#pragma unroll
      for (int r = 0; r < 16; ++r) {
        int c = ct * 32 + (r & 3) + 8 * (r >> 2) + 4 * h;
        Ob[half][c][ln] += o[ct][r] * a;
      }
  }
  __syncthreads();
  // all waves: write 64 channels each
#pragma unroll
  for (int ct2 = 0; ct2 < 2; ++ct2)
#pragma unroll
    for (int r = 0; r < 16; ++r) {
      int c = w * 64 + ct2 * 32 + (r & 3) + 8 * (r >> 2) + 4 * h;
      size_t idx = ((size_t)b * C_ + c) * N_ + n0 + ln;
      out[idx] = (Ob[0][c][ln] + Ob[1][c][ln]) * inv + x[idx];
    }
}

extern "C" void kernel_launch(void* const* d_in, const int* in_sizes, int n_in,
                              void* d_out, int out_size, void* d_ws, size_t ws_size,
                              hipStream_t stream) {
  const float* x  = (const float*)d_in[0];
  const float* wq = (const float*)d_in[1];
  const float* bq = (const float*)d_in[2];
  const float* wk = (const float*)d_in[3];
  const float* bk = (const float*)d_in[4];
  const float* wv = (const float*)d_in[5];
  const float* bv = (const float*)d_in[6];
  float* out = (float*)d_out;

  bf16* xT = (bf16*)d_ws;
  bf16* Qt = xT + (size_t)B_ * N_ * C_;
  bf16* Kt = Qt + (size_t)B_ * N_ * C8_;
  bf16* Vt = Kt + (size_t)B_ * N_ * C8_;
  bf16* Wb = Vt + (size_t)B_ * N_ * C_;

  k_convw<<<dim3(80), dim3(256), 0, stream>>>(wq, wk, wv, Wb);
  k_transpose<<<dim3(2048), dim3(256), 0, stream>>>(x, xT);
  k_proj_qk<<<dim3(256, 2), dim3(256), 0, stream>>>(xT, Wb, bq, bk, Qt, Kt);
  k_proj_v<<<dim3(2048), dim3(256), 0, stream>>>(xT, Wb, bv, Vt);
  k_attn<<<dim3(1024), dim3(256), 0, stream>>>(Qt, Kt, Vt, x, out);
}

// Round 7
// 185.345 us; speedup vs baseline: 1.1727x; 1.1727x over previous
//
#include <hip/hip_runtime.h>

#define B_ 8
#define C_ 256
#define C8_ 32
#define N_ 4096

typedef __bf16 bf16;
typedef __bf16 bf16x4 __attribute__((ext_vector_type(4)));
typedef __bf16 bf16x8 __attribute__((ext_vector_type(8)));
typedef float f32x4 __attribute__((ext_vector_type(4)));
typedef float f32x16 __attribute__((ext_vector_type(16)));

#if __has_builtin(__builtin_amdgcn_exp2f)
#define EXP2 __builtin_amdgcn_exp2f
#else
#define EXP2 exp2f
#endif

#define CVTPK(lo, hi) ({ unsigned int _w;                                     \
  asm("v_cvt_pk_bf16_f32 %0, %1, %2" : "=v"(_w) : "v"(lo), "v"(hi)); _w; })
#define LSWAP(a, b) asm("v_permlane32_swap_b32 %0, %1" : "+v"(a), "+v"(b))

// async global->LDS, 16B per lane; dest = uniform base + lane*16
#define GLD16(gp, lp) __builtin_amdgcn_global_load_lds(                       \
    (const __attribute__((address_space(1))) void*)(gp),                      \
    (__attribute__((address_space(3))) void*)(lp), 16, 0, 0)
#define VMW(n) do { asm volatile("s_waitcnt vmcnt(" n ")" ::: "memory");      \
    __builtin_amdgcn_sched_barrier(0); } while (0)

// ---------------- weights f32 -> bf16 (once) --------------------------------
__global__ __launch_bounds__(256) void k_convw(const float* __restrict__ wq,
    const float* __restrict__ wk, const float* __restrict__ wv,
    bf16* __restrict__ Wb) {
  int i = (blockIdx.x * 256 + threadIdx.x) * 4;
  const float* src; int off;
  if (i < 8192) { src = wq; off = i; }
  else if (i < 16384) { src = wk; off = i - 8192; }
  else { src = wv; off = i - 16384; }
  f32x4 v = *reinterpret_cast<const f32x4*>(src + off);
  bf16x4 o;
  o[0] = (bf16)v[0]; o[1] = (bf16)v[1]; o[2] = (bf16)v[2]; o[3] = (bf16)v[3];
  *reinterpret_cast<bf16x4*>(Wb + i) = o;
}

// ---------------- transpose + convert: x[b][c][n] f32 -> xT[b][n][c] bf16 ----
__global__ __launch_bounds__(256) void k_transpose(const float* __restrict__ x,
                                                   bf16* __restrict__ xT) {
  __shared__ bf16 t[64][72];
  int bid = blockIdx.x;
  int b = bid & 7, rem = bid >> 3;
  int c0 = (rem >> 6) * 64, n0 = (rem & 63) * 64;
  int tid = threadIdx.x;
#pragma unroll
  for (int r = 0; r < 4; ++r) {
    int cc = r * 16 + (tid >> 4);
    int j = (tid & 15) * 4;
    f32x4 v = *reinterpret_cast<const f32x4*>(
        x + ((size_t)b * C_ + c0 + cc) * N_ + n0 + j);
    bf16x4 o;
    o[0] = (bf16)v[0]; o[1] = (bf16)v[1]; o[2] = (bf16)v[2]; o[3] = (bf16)v[3];
    *reinterpret_cast<bf16x4*>(&t[cc][j]) = o;
  }
  __syncthreads();
#pragma unroll
  for (int r = 0; r < 2; ++r) {
    int nn = r * 32 + (tid >> 3);
    int c8 = (tid & 7) * 8;
    bf16x8 o;
#pragma unroll
    for (int k = 0; k < 8; ++k) o[k] = t[c8 + k][nn];
    *reinterpret_cast<bf16x8*>(
        xT + ((size_t)b * N_ + n0 + nn) * C_ + c0 + c8) = o;
  }
}

// ------------- Q/K projection. Q: [b][n][32] scaled by log2e.  --------------
// K: FRAGMENT-MAJOR Kt[b][mt][f][64][8]: Kt'[...] = K[c=f*16+(L>>5)*8+e][m=mt*32+(L&31)]
__global__ __launch_bounds__(256) void k_proj_qk(const bf16* __restrict__ xT,
    const bf16* __restrict__ Wb,
    const float* __restrict__ bq, const float* __restrict__ bk,
    bf16* __restrict__ Qt, bf16* __restrict__ Kt) {
  int bid = blockIdx.x;
  int b = bid & 7, nt = bid >> 3;
  const bf16* W = Wb + (blockIdx.y ? 8192 : 0);
  const float* bias = blockIdx.y ? bk : bq;
  int tid = threadIdx.x, lane = tid & 63, w = tid >> 6;
  int ln = lane & 31, h = lane >> 5;
  int n0 = nt * 128 + w * 32;
  const bf16* xp = xT + ((size_t)b * N_ + n0 + ln) * C_ + h * 8;
  const bf16* wp = W + (size_t)ln * C_ + h * 8;
  f32x16 acc;
#pragma unroll
  for (int r = 0; r < 16; ++r) acc[r] = 0.f;
#pragma unroll
  for (int ck = 0; ck < C_; ck += 16) {
    bf16x8 af = *reinterpret_cast<const bf16x8*>(xp + ck);
    bf16x8 bfg = *reinterpret_cast<const bf16x8*>(wp + ck);
    acc = __builtin_amdgcn_mfma_f32_32x32x16_bf16(af, bfg, acc, 0, 0, 0);
  }
  float bb = bias[ln];
  if (blockIdx.y) {   // K -> fragment-major
    int f = (ln >> 4) & 1, hA = (ln >> 3) & 1, e = ln & 7;
#pragma unroll
    for (int r = 0; r < 16; ++r) {
      int n = n0 + (r & 3) + 8 * (r >> 2) + 4 * h;
      int mt = n >> 5, lm = n & 31;
      Kt[((size_t)(b * 128 + mt) * 2 + f) * 512 + (lm + hA * 32) * 8 + e] =
          (bf16)(acc[r] + bb);
    }
  } else {            // Q -> n-major, log2e folded
#pragma unroll
    for (int r = 0; r < 16; ++r) {
      int n = n0 + (r & 3) + 8 * (r >> 2) + 4 * h;
      Qt[((size_t)b * N_ + n) * C8_ + ln] = (bf16)((acc[r] + bb) * 1.44269504f);
    }
  }
}

// ------------- V projection -> FRAGMENT-MAJOR Vt[b][mt][f=ct*2+j][64][8] ----
// Vt'[...] = V[c=ct*32+(L&31)][m=mt*32+j*16+(L>>5)*8+e]
__global__ __launch_bounds__(256) void k_proj_v(const bf16* __restrict__ xT,
    const bf16* __restrict__ Wb, const float* __restrict__ bv,
    bf16* __restrict__ Vt) {
  int bid = blockIdx.x;
  int b = bid & 7, rem = bid >> 3;
  int ot = rem >> 5, nt = rem & 31;
  int tid = threadIdx.x, lane = tid & 63, w = tid >> 6;
  int ln = lane & 31, h = lane >> 5;
  int o0 = ot * 32;
  int n0 = nt * 128 + w * 32;
  const bf16* wp = Wb + 16384 + (size_t)(o0 + ln) * C_ + h * 8;
  const bf16* xp = xT + ((size_t)b * N_ + n0 + ln) * C_ + h * 8;
  f32x16 acc;
#pragma unroll
  for (int r = 0; r < 16; ++r) acc[r] = 0.f;
#pragma unroll
  for (int ck = 0; ck < C_; ck += 16) {
    bf16x8 afg = *reinterpret_cast<const bf16x8*>(wp + ck);
    bf16x8 bfg = *reinterpret_cast<const bf16x8*>(xp + ck);
    acc = __builtin_amdgcn_mfma_f32_32x32x16_bf16(afg, bfg, acc, 0, 0, 0);
  }
  int mt = n0 >> 5;
  bf16* tb = Vt + (size_t)(b * 128 + mt) * 8192;
  int ct = o0 >> 5;
  int j = (ln >> 4) & 1, hA = (ln >> 3) & 1, e = ln & 7;
#pragma unroll
  for (int r = 0; r < 16; ++r) {
    int cc = (r & 3) + 8 * (r >> 2) + 4 * h;     // c - o0
    tb[(ct * 2 + j) * 512 + (cc + hA * 32) * 8 + e] = (bf16)(acc[r] + bv[o0 + cc]);
  }
}

// ---------------- flash attention: m-split + per-wave LDS V pipeline --------
// 1024 blocks x 4 waves, barrier-free main loop. Wave w owns m-quarter.
// Per iter: K(t+1)->regs (dense), DMA V(t) halves->private LDS (frag-major,
// 1KB/instr), QK+softmax covers DMA latency, vmcnt(8)->PV h0, vmcnt(0)->PV h1.
__global__ __launch_bounds__(256, 2) void k_attn(const bf16* __restrict__ Qt,
    const bf16* __restrict__ Kt, const bf16* __restrict__ Vt,
    const float* __restrict__ x, float* __restrict__ out) {
  __shared__ __align__(16) char sbuf[67584];   // V bufs (64KB) ∪ merge Ob (66KB)
  __shared__ float sML[4][2][32];
  int bid = blockIdx.x;
  int b = bid & 7;                     // batch == XCD
  int qt = bid >> 3;
  int n0 = qt * 32;
  int tid = threadIdx.x, lane = tid & 63, w = tid >> 6;
  int ln = lane & 31, h = lane >> 5;
  char* VbufA = sbuf + w * 16384;
  char* VbufB = VbufA + 8192;

  const bf16* qp = Qt + ((size_t)b * N_ + n0 + ln) * C8_ + h * 8;
  bf16x8 qf0 = *reinterpret_cast<const bf16x8*>(qp);
  bf16x8 qf1 = *reinterpret_cast<const bf16x8*>(qp + 16);
  const bf16* Kb = Kt + (size_t)(b * 128 + w * 32) * 1024 + (size_t)lane * 8;
  const char* Vg = (const char*)(Vt + (size_t)(b * 128 + w * 32) * 8192)
                   + (size_t)lane * 16;

  f32x16 o[8];
#pragma unroll
  for (int ct = 0; ct < 8; ++ct)
#pragma unroll
    for (int r = 0; r < 16; ++r) o[ct][r] = 0.f;
  float M = -1e30f, L = 0.f;

  bf16x8 kf0 = *reinterpret_cast<const bf16x8*>(Kb);
  bf16x8 kf1 = *reinterpret_cast<const bf16x8*>(Kb + 512);

#pragma unroll 1
  for (int it = 0; it < 32; ++it) {
    // prefetch next K tile (dense 1KB loads)
    int itn = it + 1 > 31 ? 31 : it + 1;
    bf16x8 kn0 = *reinterpret_cast<const bf16x8*>(Kb + (size_t)itn * 1024);
    bf16x8 kn1 = *reinterpret_cast<const bf16x8*>(Kb + (size_t)itn * 1024 + 512);

    // DMA V(it) -> private LDS (frag-major: each instr = dense 1KB)
    const char* vg = Vg + (size_t)it * 16384;
#pragma unroll
    for (int f = 0; f < 8; ++f) GLD16(vg + f * 1024, VbufA + f * 1024);
#pragma unroll
    for (int f = 0; f < 8; ++f) GLD16(vg + 8192 + f * 1024, VbufB + f * 1024);

    // ---- S = K x Q
    f32x16 s;
#pragma unroll
    for (int r = 0; r < 16; ++r) s[r] = 0.f;
    s = __builtin_amdgcn_mfma_f32_32x32x16_bf16(kf0, qf0, s, 0, 0, 0);
    s = __builtin_amdgcn_mfma_f32_32x32x16_bf16(kf1, qf1, s, 0, 0, 0);

    // ---- softmax (covers DMA latency)
    float m0 = fmaxf(fmaxf(fmaxf(s[0], s[1]), fmaxf(s[2], s[3])),
                     fmaxf(fmaxf(s[4], s[5]), fmaxf(s[6], s[7])));
    float m1 = fmaxf(fmaxf(fmaxf(s[8], s[9]), fmaxf(s[10], s[11])),
                     fmaxf(fmaxf(s[12], s[13]), fmaxf(s[14], s[15])));
    float wm = fmaxf(m0, m1);
    wm = fmaxf(wm, __shfl_xor(wm, 32));
    bool resc = __any(wm > M + 8.f);     // defer-max (T13)
    if (resc) {
      float Mn = fmaxf(M, wm);
      float sc = EXP2(M - Mn);
      L *= sc;
#pragma unroll
      for (int ct = 0; ct < 8; ++ct)
#pragma unroll
        for (int r = 0; r < 16; ++r) o[ct][r] *= sc;
      M = Mn;
    }
#pragma unroll
    for (int r = 0; r < 16; ++r) s[r] = EXP2(s[r] - M);
    float q0 = (s[0] + s[1]) + (s[2] + s[3]);
    float q1 = (s[4] + s[5]) + (s[6] + s[7]);
    float q2 = (s[8] + s[9]) + (s[10] + s[11]);
    float q3 = (s[12] + s[13]) + (s[14] + s[15]);
    L += (q0 + q1) + (q2 + q3);

    // P -> bf16 frags in-register (T12)
    unsigned int c0 = CVTPK(s[0], s[1]),   c1 = CVTPK(s[2], s[3]);
    unsigned int c2 = CVTPK(s[4], s[5]),   c3 = CVTPK(s[6], s[7]);
    unsigned int c4 = CVTPK(s[8], s[9]),   c5 = CVTPK(s[10], s[11]);
    unsigned int c6 = CVTPK(s[12], s[13]), c7 = CVTPK(s[14], s[15]);
    LSWAP(c0, c2); LSWAP(c1, c3); LSWAP(c4, c6); LSWAP(c5, c7);
    union { unsigned int u[4]; bf16x8 v; } P0, P1;
    P0.u[0] = c0; P0.u[1] = c1; P0.u[2] = c2; P0.u[3] = c3;
    P1.u[0] = c4; P1.u[1] = c5; P1.u[2] = c6; P1.u[3] = c7;

    // ---- PV half 0 (ct 0..3) from VbufA
    VMW("8");                            // h0 DMA complete (h1 may remain)
    __builtin_amdgcn_s_setprio(1);
#pragma unroll
    for (int ct = 0; ct < 4; ++ct) {
      bf16x8 vf0 = *reinterpret_cast<const bf16x8*>(VbufA + (2 * ct) * 1024 + lane * 16);
      bf16x8 vf1 = *reinterpret_cast<const bf16x8*>(VbufA + (2 * ct + 1) * 1024 + lane * 16);
      o[ct] = __builtin_amdgcn_mfma_f32_32x32x16_bf16(vf0, P0.v, o[ct], 0, 0, 0);
      o[ct] = __builtin_amdgcn_mfma_f32_32x32x16_bf16(vf1, P1.v, o[ct], 0, 0, 0);
    }
    __builtin_amdgcn_s_setprio(0);

    // ---- PV half 1 (ct 4..7) from VbufB
    VMW("0");                            // h1 DMA complete
    __builtin_amdgcn_s_setprio(1);
#pragma unroll
    for (int ct = 4; ct < 8; ++ct) {
      bf16x8 vf0 = *reinterpret_cast<const bf16x8*>(VbufB + (2 * (ct - 4)) * 1024 + lane * 16);
      bf16x8 vf1 = *reinterpret_cast<const bf16x8*>(VbufB + (2 * (ct - 4) + 1) * 1024 + lane * 16);
      o[ct] = __builtin_amdgcn_mfma_f32_32x32x16_bf16(vf0, P0.v, o[ct], 0, 0, 0);
      o[ct] = __builtin_amdgcn_mfma_f32_32x32x16_bf16(vf1, P1.v, o[ct], 0, 0, 0);
    }
    __builtin_amdgcn_s_setprio(0);

    kf0 = kn0; kf1 = kn1;
  }

  // ---- 4-way merge (V bufs dead after the barrier; Ob aliases them) ----
  float (*Ob)[256][33] = reinterpret_cast<float (*)[256][33]>(sbuf);
  L += __shfl_xor(L, 32);
  if (lane < 32) { sML[w][0][lane] = M; sML[w][1][lane] = L; }
  __syncthreads();
  float Ms = fmaxf(fmaxf(sML[0][0][ln], sML[1][0][ln]),
                   fmaxf(sML[2][0][ln], sML[3][0][ln]));
  float Lt = sML[0][1][ln] * EXP2(sML[0][0][ln] - Ms)
           + sML[1][1][ln] * EXP2(sML[1][0][ln] - Ms)
           + sML[2][1][ln] * EXP2(sML[2][0][ln] - Ms)
           + sML[3][1][ln] * EXP2(sML[3][0][ln] - Ms);
  float inv = 1.f / Lt;
  float a = EXP2(M - Ms);
  int half = w >> 1;
  if (!(w & 1)) {
#pragma unroll
    for (int ct = 0; ct < 8; ++ct)
#pragma unroll
      for (int r = 0; r < 16; ++r) {
        int c = ct * 32 + (r & 3) + 8 * (r >> 2) + 4 * h;
        Ob[half][c][ln] = o[ct][r] * a;
      }
  }
  __syncthreads();
  if (w & 1) {
#pragma unroll
    for (int ct = 0; ct < 8; ++ct)
#pragma unroll
      for (int r = 0; r < 16; ++r) {
        int c = ct * 32 + (r & 3) + 8 * (r >> 2) + 4 * h;
        Ob[half][c][ln] += o[ct][r] * a;
      }
  }
  __syncthreads();
#pragma unroll
  for (int ct2 = 0; ct2 < 2; ++ct2)
#pragma unroll
    for (int r = 0; r < 16; ++r) {
      int c = w * 64 + ct2 * 32 + (r & 3) + 8 * (r >> 2) + 4 * h;
      size_t idx = ((size_t)b * C_ + c) * N_ + n0 + ln;
      out[idx] = (Ob[0][c][ln] + Ob[1][c][ln]) * inv + x[idx];
    }
}

extern "C" void kernel_launch(void* const* d_in, const int* in_sizes, int n_in,
                              void* d_out, int out_size, void* d_ws, size_t ws_size,
                              hipStream_t stream) {
  const float* x  = (const float*)d_in[0];
  const float* wq = (const float*)d_in[1];
  const float* bq = (const float*)d_in[2];
  const float* wk = (const float*)d_in[3];
  const float* bk = (const float*)d_in[4];
  const float* wv = (const float*)d_in[5];
  const float* bv = (const float*)d_in[6];
  float* out = (float*)d_out;

  bf16* xT = (bf16*)d_ws;
  bf16* Qt = xT + (size_t)B_ * N_ * C_;
  bf16* Kt = Qt + (size_t)B_ * N_ * C8_;
  bf16* Vt = Kt + (size_t)B_ * N_ * C8_;
  bf16* Wb = Vt + (size_t)B_ * N_ * C_;

  k_convw<<<dim3(80), dim3(256), 0, stream>>>(wq, wk, wv, Wb);
  k_transpose<<<dim3(2048), dim3(256), 0, stream>>>(x, xT);
  k_proj_qk<<<dim3(256, 2), dim3(256), 0, stream>>>(xT, Wb, bq, bk, Qt, Kt);
  k_proj_v<<<dim3(2048), dim3(256), 0, stream>>>(xT, Wb, bv, Vt);
  k_attn<<<dim3(1024), dim3(256), 0, stream>>>(Qt, Kt, Vt, x, out);
}